// Round 1
// baseline (813.199 us; speedup 1.0000x reference)
//
#include <hip/hip_runtime.h>
#include <math.h>

#define F 64
#define NP 16

__global__ void k_deg(const int* __restrict__ dst, float* __restrict__ deg, int nE) {
    int i = blockIdx.x * blockDim.x + threadIdx.x;
    if (i < nE) atomicAdd(&deg[dst[i]], 1.0f);
}

__global__ void k_invdeg(float* __restrict__ deg, int n) {
    int i = blockIdx.x * blockDim.x + threadIdx.x;
    if (i < n) { float d = deg[i]; deg[i] = (d > 0.f) ? (1.f / d) : 0.f; }
}

// one wave (64 lanes) per edge; lane f handles feature f
__global__ void k_scatter(const int* __restrict__ src, const int* __restrict__ dst,
                          const float* __restrict__ x, float* __restrict__ agg, int nE) {
    int t = blockIdx.x * blockDim.x + threadIdx.x;
    int e = t >> 6;
    if (e >= nE) return;
    int f = t & 63;
    int s = src[e], d = dst[e];
    atomicAdd(&agg[(size_t)d * F + f], x[(size_t)s * F + f]);
}

// per-node dense transform: out = relu(x*Ws + (agg*inv)*Wn + b)
// block = 256 threads = 4 waves = 4 nodes per iteration, grid-stride
__global__ __launch_bounds__(256) void k_layer1(
    const float* __restrict__ x, const float* __restrict__ agg,
    const float* __restrict__ invdeg, const float* __restrict__ Ws,
    const float* __restrict__ Wn, const float* __restrict__ b,
    float* __restrict__ out, int nN)
{
    __shared__ float sWs[F * F], sWn[F * F];
    __shared__ float sx[4][F], sa[4][F];
    for (int i = threadIdx.x; i < F * F; i += 256) { sWs[i] = Ws[i]; sWn[i] = Wn[i]; }
    int w = threadIdx.x >> 6, j = threadIdx.x & 63;
    float bj = b[j];
    __syncthreads();
    for (int base = blockIdx.x * 4; base < nN; base += gridDim.x * 4) {
        int n = base + w;
        if (n < nN) {
            sx[w][j] = x[(size_t)n * F + j];
            sa[w][j] = agg[(size_t)n * F + j] * invdeg[n];
        }
        __syncthreads();
        if (n < nN) {
            float acc = bj;
#pragma unroll
            for (int k = 0; k < F; ++k)
                acc += sx[w][k] * sWs[k * F + j] + sa[w][k] * sWn[k * F + j];
            out[(size_t)n * F + j] = fmaxf(acc, 0.f);
        }
        __syncthreads();
    }
}

// layer2 + FC + softmax fused; one wave per node
__global__ __launch_bounds__(256) void k_layer2(
    const float* __restrict__ x, const float* __restrict__ agg,
    const float* __restrict__ invdeg, const float* __restrict__ Ws,
    const float* __restrict__ Wn, const float* __restrict__ b,
    const float* __restrict__ Wfc, const float* __restrict__ bfc,
    float* __restrict__ out, int nN)
{
    __shared__ float sWs[F * F], sWn[F * F], sWfc[F * NP];
    __shared__ float sx[4][F], sa[4][F], sh[4][F];
    for (int i = threadIdx.x; i < F * F; i += 256) { sWs[i] = Ws[i]; sWn[i] = Wn[i]; }
    for (int i = threadIdx.x; i < F * NP; i += 256) sWfc[i] = Wfc[i];
    int w = threadIdx.x >> 6, j = threadIdx.x & 63;
    float bj = b[j];
    float bfcj = bfc[j & 15];
    __syncthreads();
    for (int base = blockIdx.x * 4; base < nN; base += gridDim.x * 4) {
        int n = base + w;
        if (n < nN) {
            sx[w][j] = x[(size_t)n * F + j];
            sa[w][j] = agg[(size_t)n * F + j] * invdeg[n];
        }
        __syncthreads();
        if (n < nN) {
            float acc = bj;
#pragma unroll
            for (int k = 0; k < F; ++k)
                acc += sx[w][k] * sWs[k * F + j] + sa[w][k] * sWn[k * F + j];
            sh[w][j] = fmaxf(acc, 0.f);
        }
        __syncthreads();
        if (n < nN) {
            // all lanes compute a logit (lanes 16-63 duplicate 0-15's work; harmless)
            float lg = bfcj;
#pragma unroll
            for (int k = 0; k < F; ++k)
                lg += sh[w][k] * sWfc[k * NP + (j & 15)];
            // softmax across each 16-lane group
            float m = lg;
            for (int off = 8; off; off >>= 1) m = fmaxf(m, __shfl_xor(m, off, 16));
            float e = __expf(lg - m);
            float s = e;
            for (int off = 8; off; off >>= 1) s += __shfl_xor(s, off, 16);
            if (j < NP) out[(size_t)n * NP + j] = e / s;
        }
        __syncthreads();
    }
}

extern "C" void kernel_launch(void* const* d_in, const int* in_sizes, int n_in,
                              void* d_out, int out_size, void* d_ws, size_t ws_size,
                              hipStream_t stream) {
    const float* features = (const float*)d_in[0];
    const int*   src      = (const int*)d_in[1];
    const int*   dst      = (const int*)d_in[2];
    const float* Ws1      = (const float*)d_in[3];
    const float* Wn1      = (const float*)d_in[4];
    const float* b1       = (const float*)d_in[5];
    const float* Ws2      = (const float*)d_in[6];
    const float* Wn2      = (const float*)d_in[7];
    const float* b2       = (const float*)d_in[8];
    const float* Wfc      = (const float*)d_in[9];
    const float* bfc      = (const float*)d_in[10];
    float* out = (float*)d_out;

    int nE = in_sizes[1];
    int nN = in_sizes[0] / F;

    // workspace layout (floats): deg | agg | h1
    int degPad = (nN + 255) & ~255;
    float* deg = (float*)d_ws;
    float* agg = deg + degPad;
    float* h1  = agg + (size_t)nN * F;

    // zero deg + agg in one shot
    hipMemsetAsync(deg, 0, ((size_t)degPad + (size_t)nN * F) * sizeof(float), stream);

    k_deg<<<(nE + 255) / 256, 256, 0, stream>>>(dst, deg, nE);
    k_invdeg<<<(nN + 255) / 256, 256, 0, stream>>>(deg, nN);

    int sgrid = (int)(((long long)nE * F + 255) / 256);
    k_scatter<<<sgrid, 256, 0, stream>>>(src, dst, features, agg, nE);
    k_layer1<<<2048, 256, 0, stream>>>(features, agg, deg, Ws1, Wn1, b1, h1, nN);

    hipMemsetAsync(agg, 0, (size_t)nN * F * sizeof(float), stream);
    k_scatter<<<sgrid, 256, 0, stream>>>(src, dst, h1, agg, nE);
    k_layer2<<<2048, 256, 0, stream>>>(h1, agg, deg, Ws2, Wn2, b2, Wfc, bfc, out, nN);
}

// Round 2
// 464.837 us; speedup vs baseline: 1.7494x; 1.7494x over previous
//
#include <hip/hip_runtime.h>
#include <math.h>

#define F 64
#define NP 16
#define SCAN_B 1024

__global__ void k_count(const int* __restrict__ dst, int* __restrict__ deg, int nE) {
    int i = blockIdx.x * blockDim.x + threadIdx.x;
    if (i < nE) atomicAdd(&deg[dst[i]], 1);
}

// per-chunk (SCAN_B) sums
__global__ __launch_bounds__(256) void k_bsum(const int* __restrict__ deg, int* __restrict__ bsum, int n) {
    __shared__ int sd[256];
    int base = blockIdx.x * SCAN_B;
    int s = 0;
    for (int i = threadIdx.x; i < SCAN_B; i += 256) {
        int idx = base + i;
        if (idx < n) s += deg[idx];
    }
    sd[threadIdx.x] = s; __syncthreads();
    for (int off = 128; off; off >>= 1) {
        if (threadIdx.x < off) sd[threadIdx.x] += sd[threadIdx.x + off];
        __syncthreads();
    }
    if (threadIdx.x == 0) bsum[blockIdx.x] = sd[0];
}

// single-wave exclusive scan of bsum (nb values), in place
__global__ void k_scanb(int* __restrict__ bsum, int nb) {
    int lane = threadIdx.x;  // blockDim.x == 64
    int carry = 0;
    for (int base = 0; base < nb; base += 64) {
        int idx = base + lane;
        int orig = (idx < nb) ? bsum[idx] : 0;
        int v = orig;
        for (int off = 1; off < 64; off <<= 1) {
            int t = __shfl_up(v, off);
            if (lane >= off) v += t;
        }
        if (idx < nb) bsum[idx] = carry + v - orig;  // exclusive
        carry += __shfl(v, 63);
    }
}

// per-chunk exclusive scan + chunk base; also cursor copy + inv-degree
__global__ __launch_bounds__(SCAN_B) void k_scanfinal(
    const int* __restrict__ deg, const int* __restrict__ bsum,
    int* __restrict__ rowstart, int* __restrict__ cursor,
    float* __restrict__ invd, int n)
{
    __shared__ int sd[SCAN_B];
    int idx = blockIdx.x * SCAN_B + threadIdx.x;
    int d = (idx < n) ? deg[idx] : 0;
    sd[threadIdx.x] = d; __syncthreads();
    for (int off = 1; off < SCAN_B; off <<= 1) {
        int t = (threadIdx.x >= off) ? sd[threadIdx.x - off] : 0;
        __syncthreads();
        sd[threadIdx.x] += t;
        __syncthreads();
    }
    if (idx < n) {
        int rs = bsum[blockIdx.x] + sd[threadIdx.x] - d;  // exclusive
        rowstart[idx] = rs;
        cursor[idx] = rs;
        invd[idx] = (d > 0) ? 1.0f / (float)d : 0.0f;
    }
}

__global__ void k_fill(const int* __restrict__ src, const int* __restrict__ dst,
                       int* __restrict__ cursor, int* __restrict__ csr, int nE) {
    int i = blockIdx.x * blockDim.x + threadIdx.x;
    if (i < nE) {
        int slot = atomicAdd(&cursor[dst[i]], 1);
        csr[slot] = src[i];
    }
}

// fused gather(mean) + dense transform: out = relu(x*Ws + mean(x[srcs])*Wn + b)
// one wave per node; lane f owns feature f
__global__ __launch_bounds__(256) void k_sage1(
    const float* __restrict__ x, const int* __restrict__ csr,
    const int* __restrict__ rowstart, const int* __restrict__ deg,
    const float* __restrict__ invd,
    const float* __restrict__ Ws, const float* __restrict__ Wn,
    const float* __restrict__ b, float* __restrict__ out, int nN)
{
    __shared__ float sWs[F * F], sWn[F * F];
    __shared__ float sx[4][F], sa[4][F];
    for (int i = threadIdx.x; i < F * F; i += 256) { sWs[i] = Ws[i]; sWn[i] = Wn[i]; }
    int w = threadIdx.x >> 6, j = threadIdx.x & 63;
    float bj = b[j];
    __syncthreads();
    for (int base = blockIdx.x * 4; base < nN; base += gridDim.x * 4) {
        int n = base + w;
        if (n < nN) {
            sx[w][j] = x[(size_t)n * F + j];
            int rs = rowstart[n], d = deg[n], e = rs + d;
            float a0 = 0.f, a1 = 0.f, a2 = 0.f, a3 = 0.f;
            int i = rs;
            for (; i + 4 <= e; i += 4) {
                int s0 = csr[i], s1 = csr[i + 1], s2 = csr[i + 2], s3 = csr[i + 3];
                a0 += x[(size_t)s0 * F + j];
                a1 += x[(size_t)s1 * F + j];
                a2 += x[(size_t)s2 * F + j];
                a3 += x[(size_t)s3 * F + j];
            }
            for (; i < e; ++i) a0 += x[(size_t)csr[i] * F + j];
            sa[w][j] = ((a0 + a1) + (a2 + a3)) * invd[n];
        }
        __syncthreads();
        if (n < nN) {
            float acc = bj;
#pragma unroll
            for (int k = 0; k < F; ++k)
                acc += sx[w][k] * sWs[k * F + j] + sa[w][k] * sWn[k * F + j];
            out[(size_t)n * F + j] = fmaxf(acc, 0.f);
        }
        __syncthreads();
    }
}

// layer2 fused gather + transform + FC + softmax
__global__ __launch_bounds__(256) void k_sage2(
    const float* __restrict__ x, const int* __restrict__ csr,
    const int* __restrict__ rowstart, const int* __restrict__ deg,
    const float* __restrict__ invd,
    const float* __restrict__ Ws, const float* __restrict__ Wn,
    const float* __restrict__ b, const float* __restrict__ Wfc,
    const float* __restrict__ bfc, float* __restrict__ out, int nN)
{
    __shared__ float sWs[F * F], sWn[F * F], sWfc[F * NP];
    __shared__ float sx[4][F], sa[4][F], sh[4][F];
    for (int i = threadIdx.x; i < F * F; i += 256) { sWs[i] = Ws[i]; sWn[i] = Wn[i]; }
    for (int i = threadIdx.x; i < F * NP; i += 256) sWfc[i] = Wfc[i];
    int w = threadIdx.x >> 6, j = threadIdx.x & 63;
    float bj = b[j];
    float bfcj = bfc[j & 15];
    __syncthreads();
    for (int base = blockIdx.x * 4; base < nN; base += gridDim.x * 4) {
        int n = base + w;
        if (n < nN) {
            sx[w][j] = x[(size_t)n * F + j];
            int rs = rowstart[n], d = deg[n], e = rs + d;
            float a0 = 0.f, a1 = 0.f, a2 = 0.f, a3 = 0.f;
            int i = rs;
            for (; i + 4 <= e; i += 4) {
                int s0 = csr[i], s1 = csr[i + 1], s2 = csr[i + 2], s3 = csr[i + 3];
                a0 += x[(size_t)s0 * F + j];
                a1 += x[(size_t)s1 * F + j];
                a2 += x[(size_t)s2 * F + j];
                a3 += x[(size_t)s3 * F + j];
            }
            for (; i < e; ++i) a0 += x[(size_t)csr[i] * F + j];
            sa[w][j] = ((a0 + a1) + (a2 + a3)) * invd[n];
        }
        __syncthreads();
        if (n < nN) {
            float acc = bj;
#pragma unroll
            for (int k = 0; k < F; ++k)
                acc += sx[w][k] * sWs[k * F + j] + sa[w][k] * sWn[k * F + j];
            sh[w][j] = fmaxf(acc, 0.f);
        }
        __syncthreads();
        if (n < nN) {
            float lg = bfcj;
#pragma unroll
            for (int k = 0; k < F; ++k)
                lg += sh[w][k] * sWfc[k * NP + (j & 15)];
            float m = lg;
            for (int off = 8; off; off >>= 1) m = fmaxf(m, __shfl_xor(m, off, 16));
            float e2 = __expf(lg - m);
            float s = e2;
            for (int off = 8; off; off >>= 1) s += __shfl_xor(s, off, 16);
            if (j < NP) out[(size_t)n * NP + j] = e2 / s;
        }
        __syncthreads();
    }
}

extern "C" void kernel_launch(void* const* d_in, const int* in_sizes, int n_in,
                              void* d_out, int out_size, void* d_ws, size_t ws_size,
                              hipStream_t stream) {
    const float* features = (const float*)d_in[0];
    const int*   src      = (const int*)d_in[1];
    const int*   dst      = (const int*)d_in[2];
    const float* Ws1      = (const float*)d_in[3];
    const float* Wn1      = (const float*)d_in[4];
    const float* b1       = (const float*)d_in[5];
    const float* Ws2      = (const float*)d_in[6];
    const float* Wn2      = (const float*)d_in[7];
    const float* b2       = (const float*)d_in[8];
    const float* Wfc      = (const float*)d_in[9];
    const float* bfc      = (const float*)d_in[10];
    float* out = (float*)d_out;

    int nE = in_sizes[1];
    int nN = in_sizes[0] / F;
    int nb = (nN + SCAN_B - 1) / SCAN_B;

    // workspace layout: deg(int) | rowstart(int) | cursor(int) | bsum(int,padded) | csr(int) | invd(f32) | h1(f32)
    int*   deg      = (int*)d_ws;
    int*   rowstart = deg + nN;
    int*   cursor   = rowstart + nN;
    int*   bsum     = cursor + nN;
    int*   csr      = bsum + ((nb + 255) & ~255);
    float* invd     = (float*)(csr + nE);
    float* h1       = invd + nN;

    hipMemsetAsync(deg, 0, (size_t)nN * sizeof(int), stream);

    // build CSR
    k_count<<<(nE + 255) / 256, 256, 0, stream>>>(dst, deg, nE);
    k_bsum<<<nb, 256, 0, stream>>>(deg, bsum, nN);
    k_scanb<<<1, 64, 0, stream>>>(bsum, nb);
    k_scanfinal<<<nb, SCAN_B, 0, stream>>>(deg, bsum, rowstart, cursor, invd, nN);
    k_fill<<<(nE + 255) / 256, 256, 0, stream>>>(src, dst, cursor, csr, nE);

    // fused layers
    k_sage1<<<2048, 256, 0, stream>>>(features, csr, rowstart, deg, invd,
                                      Ws1, Wn1, b1, h1, nN);
    k_sage2<<<2048, 256, 0, stream>>>(h1, csr, rowstart, deg, invd,
                                      Ws2, Wn2, b2, Wfc, bfc, out, nN);
}

// Round 3
// 435.668 us; speedup vs baseline: 1.8666x; 1.0670x over previous
//
#include <hip/hip_runtime.h>
#include <math.h>

#define F 64
#define NP 16
#define SCAN_B 1024
#define NB 8  // nodes per block iteration (one per wave, 512-thread blocks)

__global__ void k_count(const int* __restrict__ dst, int* __restrict__ deg, int nE) {
    int i = blockIdx.x * blockDim.x + threadIdx.x;
    if (i < nE) atomicAdd(&deg[dst[i]], 1);
}

// per-chunk (SCAN_B) sums
__global__ __launch_bounds__(256) void k_bsum(const int* __restrict__ deg, int* __restrict__ bsum, int n) {
    __shared__ int sd[256];
    int base = blockIdx.x * SCAN_B;
    int s = 0;
    for (int i = threadIdx.x; i < SCAN_B; i += 256) {
        int idx = base + i;
        if (idx < n) s += deg[idx];
    }
    sd[threadIdx.x] = s; __syncthreads();
    for (int off = 128; off; off >>= 1) {
        if (threadIdx.x < off) sd[threadIdx.x] += sd[threadIdx.x + off];
        __syncthreads();
    }
    if (threadIdx.x == 0) bsum[blockIdx.x] = sd[0];
}

// single-wave exclusive scan of bsum (nb values), in place
__global__ void k_scanb(int* __restrict__ bsum, int nb) {
    int lane = threadIdx.x;  // blockDim.x == 64
    int carry = 0;
    for (int base = 0; base < nb; base += 64) {
        int idx = base + lane;
        int orig = (idx < nb) ? bsum[idx] : 0;
        int v = orig;
        for (int off = 1; off < 64; off <<= 1) {
            int t = __shfl_up(v, off);
            if (lane >= off) v += t;
        }
        if (idx < nb) bsum[idx] = carry + v - orig;  // exclusive
        carry += __shfl(v, 63);
    }
}

// per-chunk exclusive scan + chunk base; also cursor copy + inv-degree
__global__ __launch_bounds__(SCAN_B) void k_scanfinal(
    const int* __restrict__ deg, const int* __restrict__ bsum,
    int* __restrict__ rowstart, int* __restrict__ cursor,
    float* __restrict__ invd, int n)
{
    __shared__ int sd[SCAN_B];
    int idx = blockIdx.x * SCAN_B + threadIdx.x;
    int d = (idx < n) ? deg[idx] : 0;
    sd[threadIdx.x] = d; __syncthreads();
    for (int off = 1; off < SCAN_B; off <<= 1) {
        int t = (threadIdx.x >= off) ? sd[threadIdx.x - off] : 0;
        __syncthreads();
        sd[threadIdx.x] += t;
        __syncthreads();
    }
    if (idx < n) {
        int rs = bsum[blockIdx.x] + sd[threadIdx.x] - d;  // exclusive
        rowstart[idx] = rs;
        cursor[idx] = rs;
        invd[idx] = (d > 0) ? 1.0f / (float)d : 0.0f;
    }
}

__global__ void k_fill(const int* __restrict__ src, const int* __restrict__ dst,
                       int* __restrict__ cursor, int* __restrict__ csr, int nE) {
    int i = blockIdx.x * blockDim.x + threadIdx.x;
    if (i < nE) {
        int slot = atomicAdd(&cursor[dst[i]], 1);
        csr[slot] = src[i];
    }
}

// fused gather(mean) + dense transform: out = relu(x*Ws + mean(x[srcs])*Wn + b)
// 512 threads = 8 waves = 8 nodes per iteration; lane f owns feature f
__global__ __launch_bounds__(512, 8) void k_sage1(
    const float* __restrict__ x, const int* __restrict__ csr,
    const int* __restrict__ rowstart, const int* __restrict__ deg,
    const float* __restrict__ invd,
    const float* __restrict__ Ws, const float* __restrict__ Wn,
    const float* __restrict__ b, float* __restrict__ out, int nN)
{
    __shared__ float sWs[F * F], sWn[F * F];
    __shared__ float sx[NB][F], sa[NB][F];
    {
        const float4* Ws4 = (const float4*)Ws;
        const float4* Wn4 = (const float4*)Wn;
        float4* sWs4 = (float4*)sWs; float4* sWn4 = (float4*)sWn;
        for (int i = threadIdx.x; i < F * F / 4; i += 512) { sWs4[i] = Ws4[i]; sWn4[i] = Wn4[i]; }
    }
    int w = threadIdx.x >> 6, j = threadIdx.x & 63;
    float bj = b[j];
    __syncthreads();
    for (int base = blockIdx.x * NB; base < nN; base += gridDim.x * NB) {
        int n = base + w;
        if (n < nN) {
            sx[w][j] = x[(unsigned)(n * F) + j];
            int rs = rowstart[n], d = deg[n], e = rs + d;
            float a0 = 0.f, a1 = 0.f, a2 = 0.f, a3 = 0.f;
            int i = rs;
            for (; i + 4 <= e; i += 4) {
                int s0 = csr[i], s1 = csr[i + 1], s2 = csr[i + 2], s3 = csr[i + 3];
                a0 += x[(unsigned)(s0 * F) + j];
                a1 += x[(unsigned)(s1 * F) + j];
                a2 += x[(unsigned)(s2 * F) + j];
                a3 += x[(unsigned)(s3 * F) + j];
            }
            for (; i < e; ++i) a0 += x[(unsigned)(csr[i] * F) + j];
            sa[w][j] = ((a0 + a1) + (a2 + a3)) * invd[n];
        }
        __syncthreads();
        if (n < nN) {
            float acc = bj;
#pragma unroll
            for (int k = 0; k < F; ++k)
                acc += sx[w][k] * sWs[k * F + j] + sa[w][k] * sWn[k * F + j];
            out[(unsigned)(n * F) + j] = fmaxf(acc, 0.f);
        }
        __syncthreads();
    }
}

// layer2 fused gather + transform + FC + softmax; Wfc/bfc read from global (L1-resident)
__global__ __launch_bounds__(512, 8) void k_sage2(
    const float* __restrict__ x, const int* __restrict__ csr,
    const int* __restrict__ rowstart, const int* __restrict__ deg,
    const float* __restrict__ invd,
    const float* __restrict__ Ws, const float* __restrict__ Wn,
    const float* __restrict__ b, const float* __restrict__ Wfc,
    const float* __restrict__ bfc, float* __restrict__ out, int nN)
{
    __shared__ float sWs[F * F], sWn[F * F];
    __shared__ float sx[NB][F], sa[NB][F], sh[NB][F];
    {
        const float4* Ws4 = (const float4*)Ws;
        const float4* Wn4 = (const float4*)Wn;
        float4* sWs4 = (float4*)sWs; float4* sWn4 = (float4*)sWn;
        for (int i = threadIdx.x; i < F * F / 4; i += 512) { sWs4[i] = Ws4[i]; sWn4[i] = Wn4[i]; }
    }
    int w = threadIdx.x >> 6, j = threadIdx.x & 63;
    float bj = b[j];
    float bfcj = bfc[j & 15];
    __syncthreads();
    for (int base = blockIdx.x * NB; base < nN; base += gridDim.x * NB) {
        int n = base + w;
        if (n < nN) {
            sx[w][j] = x[(unsigned)(n * F) + j];
            int rs = rowstart[n], d = deg[n], e = rs + d;
            float a0 = 0.f, a1 = 0.f, a2 = 0.f, a3 = 0.f;
            int i = rs;
            for (; i + 4 <= e; i += 4) {
                int s0 = csr[i], s1 = csr[i + 1], s2 = csr[i + 2], s3 = csr[i + 3];
                a0 += x[(unsigned)(s0 * F) + j];
                a1 += x[(unsigned)(s1 * F) + j];
                a2 += x[(unsigned)(s2 * F) + j];
                a3 += x[(unsigned)(s3 * F) + j];
            }
            for (; i < e; ++i) a0 += x[(unsigned)(csr[i] * F) + j];
            sa[w][j] = ((a0 + a1) + (a2 + a3)) * invd[n];
        }
        __syncthreads();
        if (n < nN) {
            float acc = bj;
#pragma unroll
            for (int k = 0; k < F; ++k)
                acc += sx[w][k] * sWs[k * F + j] + sa[w][k] * sWn[k * F + j];
            sh[w][j] = fmaxf(acc, 0.f);
        }
        __syncthreads();
        if (n < nN) {
            float lg = bfcj;
#pragma unroll
            for (int k = 0; k < F; ++k)
                lg += sh[w][k] * Wfc[k * NP + (j & 15)];
            float m = lg;
            for (int off = 8; off; off >>= 1) m = fmaxf(m, __shfl_xor(m, off, 16));
            float e2 = __expf(lg - m);
            float s = e2;
            for (int off = 8; off; off >>= 1) s += __shfl_xor(s, off, 16);
            if (j < NP) out[(unsigned)(n * NP) + j] = e2 / s;
        }
        __syncthreads();
    }
}

extern "C" void kernel_launch(void* const* d_in, const int* in_sizes, int n_in,
                              void* d_out, int out_size, void* d_ws, size_t ws_size,
                              hipStream_t stream) {
    const float* features = (const float*)d_in[0];
    const int*   src      = (const int*)d_in[1];
    const int*   dst      = (const int*)d_in[2];
    const float* Ws1      = (const float*)d_in[3];
    const float* Wn1      = (const float*)d_in[4];
    const float* b1       = (const float*)d_in[5];
    const float* Ws2      = (const float*)d_in[6];
    const float* Wn2      = (const float*)d_in[7];
    const float* b2       = (const float*)d_in[8];
    const float* Wfc      = (const float*)d_in[9];
    const float* bfc      = (const float*)d_in[10];
    float* out = (float*)d_out;

    int nE = in_sizes[1];
    int nN = in_sizes[0] / F;
    int nb = (nN + SCAN_B - 1) / SCAN_B;

    // workspace layout: deg(int) | rowstart(int) | cursor(int) | bsum(int,padded) | csr(int) | invd(f32) | h1(f32)
    int*   deg      = (int*)d_ws;
    int*   rowstart = deg + nN;
    int*   cursor   = rowstart + nN;
    int*   bsum     = cursor + nN;
    int*   csr      = bsum + ((nb + 255) & ~255);
    float* invd     = (float*)(csr + nE);
    float* h1       = invd + nN;

    hipMemsetAsync(deg, 0, (size_t)nN * sizeof(int), stream);

    // build CSR
    k_count<<<(nE + 255) / 256, 256, 0, stream>>>(dst, deg, nE);
    k_bsum<<<nb, 256, 0, stream>>>(deg, bsum, nN);
    k_scanb<<<1, 64, 0, stream>>>(bsum, nb);
    k_scanfinal<<<nb, SCAN_B, 0, stream>>>(deg, bsum, rowstart, cursor, invd, nN);
    k_fill<<<(nE + 255) / 256, 256, 0, stream>>>(src, dst, cursor, csr, nE);

    // fused layers: 1024 blocks = 4 blocks/CU x 256 CUs, grid-stride
    k_sage1<<<1024, 512, 0, stream>>>(features, csr, rowstart, deg, invd,
                                      Ws1, Wn1, b1, h1, nN);
    k_sage2<<<1024, 512, 0, stream>>>(h1, csr, rowstart, deg, invd,
                                      Ws2, Wn2, b2, Wfc, bfc, out, nN);
}

// Round 4
// 376.484 us; speedup vs baseline: 2.1600x; 1.1572x over previous
//
#include <hip/hip_runtime.h>
#include <math.h>

#define F 64
#define NP 16
#define SCAN_B 1024

// ---------------- CSR build ----------------

__global__ void k_count(const int* __restrict__ dst, int* __restrict__ deg, int nE) {
    int i = blockIdx.x * blockDim.x + threadIdx.x;
    if (i < nE) atomicAdd(&deg[dst[i]], 1);
}

__global__ __launch_bounds__(256) void k_bsum(const int* __restrict__ deg, int* __restrict__ bsum, int n) {
    __shared__ int sd[256];
    int base = blockIdx.x * SCAN_B;
    int s = 0;
    for (int i = threadIdx.x; i < SCAN_B; i += 256) {
        int idx = base + i;
        if (idx < n) s += deg[idx];
    }
    sd[threadIdx.x] = s; __syncthreads();
    for (int off = 128; off; off >>= 1) {
        if (threadIdx.x < off) sd[threadIdx.x] += sd[threadIdx.x + off];
        __syncthreads();
    }
    if (threadIdx.x == 0) bsum[blockIdx.x] = sd[0];
}

__global__ void k_scanb(int* __restrict__ bsum, int nb) {
    int lane = threadIdx.x;  // blockDim.x == 64
    int carry = 0;
    for (int base = 0; base < nb; base += 64) {
        int idx = base + lane;
        int orig = (idx < nb) ? bsum[idx] : 0;
        int v = orig;
        for (int off = 1; off < 64; off <<= 1) {
            int t = __shfl_up(v, off);
            if (lane >= off) v += t;
        }
        if (idx < nb) bsum[idx] = carry + v - orig;  // exclusive
        carry += __shfl(v, 63);
    }
}

__global__ __launch_bounds__(SCAN_B) void k_scanfinal(
    const int* __restrict__ deg, const int* __restrict__ bsum,
    int* __restrict__ rowstart, int* __restrict__ cursor,
    float* __restrict__ invd, int n)
{
    __shared__ int sd[SCAN_B];
    int idx = blockIdx.x * SCAN_B + threadIdx.x;
    int d = (idx < n) ? deg[idx] : 0;
    sd[threadIdx.x] = d; __syncthreads();
    for (int off = 1; off < SCAN_B; off <<= 1) {
        int t = (threadIdx.x >= off) ? sd[threadIdx.x - off] : 0;
        __syncthreads();
        sd[threadIdx.x] += t;
        __syncthreads();
    }
    if (idx < n) {
        int rs = bsum[blockIdx.x] + sd[threadIdx.x] - d;  // exclusive
        rowstart[idx] = rs;
        cursor[idx] = rs;
        invd[idx] = (d > 0) ? 1.0f / (float)d : 0.0f;
    }
}

__global__ void k_fill(const int* __restrict__ src, const int* __restrict__ dst,
                       int* __restrict__ cursor, int* __restrict__ csr, int nE) {
    int i = blockIdx.x * blockDim.x + threadIdx.x;
    if (i < nE) {
        int slot = atomicAdd(&cursor[dst[i]], 1);
        csr[slot] = src[i];
    }
}

// ---------------- gather: agg[n] = mean over neighbors of x[src] ----------------
// one wave per node; 4 lane-groups of 16 each process one edge via float4 row loads
__global__ __launch_bounds__(256) void k_gather(
    const float* __restrict__ x, const int* __restrict__ csr,
    const int* __restrict__ rowstart, const int* __restrict__ deg,
    const float* __restrict__ invd, float* __restrict__ agg, int nN)
{
    int wid = (blockIdx.x * blockDim.x + threadIdx.x) >> 6;
    int nW  = (gridDim.x * blockDim.x) >> 6;
    int lane = threadIdx.x & 63;
    int g = lane >> 4, c = lane & 15;
    for (int n = wid; n < nN; n += nW) {
        int rs = rowstart[n], e = rs + deg[n];
        float ax = 0.f, ay = 0.f, az = 0.f, aw = 0.f;
        int i = rs + g;
        while (i + 4 < e) {  // 2 edges in flight per group = 8 per wave
            int s0 = csr[i], s1 = csr[i + 4];
            float4 v0 = *(const float4*)(x + (unsigned)(s0 * F) + c * 4);
            float4 v1 = *(const float4*)(x + (unsigned)(s1 * F) + c * 4);
            ax += v0.x + v1.x; ay += v0.y + v1.y;
            az += v0.z + v1.z; aw += v0.w + v1.w;
            i += 8;
        }
        if (i < e) {
            int s0 = csr[i];
            float4 v0 = *(const float4*)(x + (unsigned)(s0 * F) + c * 4);
            ax += v0.x; ay += v0.y; az += v0.z; aw += v0.w;
        }
        // fold the 4 lane-groups together (every lane ends with the full sum)
        ax += __shfl_xor(ax, 16); ay += __shfl_xor(ay, 16);
        az += __shfl_xor(az, 16); aw += __shfl_xor(aw, 16);
        ax += __shfl_xor(ax, 32); ay += __shfl_xor(ay, 32);
        az += __shfl_xor(az, 32); aw += __shfl_xor(aw, 32);
        float iv = invd[n];
        if (lane < 16) {
            float4 r; r.x = ax * iv; r.y = ay * iv; r.z = az * iv; r.w = aw * iv;
            *(float4*)(agg + (unsigned)(n * F) + lane * 4) = r;
        }
    }
}

// ---------------- transform 1: h = relu(x*Ws + agg*Wn + b) ----------------
// weights live in VGPRs (lane j holds column j); x/agg broadcast via v_readlane.
// No LDS anywhere.
__global__ __launch_bounds__(256, 2) void k_xform1(
    const float* __restrict__ x, const float* __restrict__ agg,
    const float* __restrict__ Ws, const float* __restrict__ Wn,
    const float* __restrict__ b, float* __restrict__ out, int nN)
{
    int lane = threadIdx.x & 63;
    float ws[F], wn[F];
#pragma unroll
    for (int k = 0; k < F; ++k) { ws[k] = Ws[k * F + lane]; wn[k] = Wn[k * F + lane]; }
    float bj = b[lane];
    int wid = (blockIdx.x * blockDim.x + threadIdx.x) >> 6;
    int nW  = (gridDim.x * blockDim.x) >> 6;
    int n = wid;
    float vx = 0.f, va = 0.f;
    if (n < nN) { vx = x[(unsigned)(n * F) + lane]; va = agg[(unsigned)(n * F) + lane]; }
    while (n < nN) {
        int n2 = n + nW;
        float vx2 = 0.f, va2 = 0.f;
        if (n2 < nN) { vx2 = x[(unsigned)(n2 * F) + lane]; va2 = agg[(unsigned)(n2 * F) + lane]; }
        float a0 = bj, a1 = 0.f, a2 = 0.f, a3 = 0.f;
#pragma unroll
        for (int k = 0; k < F; k += 2) {
            float x0 = __int_as_float(__builtin_amdgcn_readlane(__float_as_int(vx), k));
            float s0 = __int_as_float(__builtin_amdgcn_readlane(__float_as_int(va), k));
            float x1 = __int_as_float(__builtin_amdgcn_readlane(__float_as_int(vx), k + 1));
            float s1 = __int_as_float(__builtin_amdgcn_readlane(__float_as_int(va), k + 1));
            a0 = fmaf(x0, ws[k], a0);
            a1 = fmaf(s0, wn[k], a1);
            a2 = fmaf(x1, ws[k + 1], a2);
            a3 = fmaf(s1, wn[k + 1], a3);
        }
        out[(unsigned)(n * F) + lane] = fmaxf((a0 + a1) + (a2 + a3), 0.f);
        n = n2; vx = vx2; va = va2;
    }
}

// ---------------- transform 2 + FC + softmax ----------------
__global__ __launch_bounds__(256, 2) void k_xform2(
    const float* __restrict__ x, const float* __restrict__ agg,
    const float* __restrict__ Ws, const float* __restrict__ Wn,
    const float* __restrict__ b, const float* __restrict__ Wfc,
    const float* __restrict__ bfc, float* __restrict__ out, int nN)
{
    int lane = threadIdx.x & 63;
    float ws[F], wn[F], wf[F];
#pragma unroll
    for (int k = 0; k < F; ++k) {
        ws[k] = Ws[k * F + lane];
        wn[k] = Wn[k * F + lane];
        wf[k] = Wfc[k * NP + (lane & 15)];
    }
    float bj = b[lane], bf = bfc[lane & 15];
    int wid = (blockIdx.x * blockDim.x + threadIdx.x) >> 6;
    int nW  = (gridDim.x * blockDim.x) >> 6;
    int n = wid;
    float vx = 0.f, va = 0.f;
    if (n < nN) { vx = x[(unsigned)(n * F) + lane]; va = agg[(unsigned)(n * F) + lane]; }
    while (n < nN) {
        int n2 = n + nW;
        float vx2 = 0.f, va2 = 0.f;
        if (n2 < nN) { vx2 = x[(unsigned)(n2 * F) + lane]; va2 = agg[(unsigned)(n2 * F) + lane]; }
        float a0 = bj, a1 = 0.f, a2 = 0.f, a3 = 0.f;
#pragma unroll
        for (int k = 0; k < F; k += 2) {
            float x0 = __int_as_float(__builtin_amdgcn_readlane(__float_as_int(vx), k));
            float s0 = __int_as_float(__builtin_amdgcn_readlane(__float_as_int(va), k));
            float x1 = __int_as_float(__builtin_amdgcn_readlane(__float_as_int(vx), k + 1));
            float s1 = __int_as_float(__builtin_amdgcn_readlane(__float_as_int(va), k + 1));
            a0 = fmaf(x0, ws[k], a0);
            a1 = fmaf(s0, wn[k], a1);
            a2 = fmaf(x1, ws[k + 1], a2);
            a3 = fmaf(s1, wn[k + 1], a3);
        }
        float h = fmaxf((a0 + a1) + (a2 + a3), 0.f);
        // FC: logit for class p = lane&15 (4 redundant copies across lane groups)
        float l0 = bf, l1 = 0.f, l2 = 0.f, l3 = 0.f;
#pragma unroll
        for (int k = 0; k < F; k += 4) {
            float h0 = __int_as_float(__builtin_amdgcn_readlane(__float_as_int(h), k));
            float h1v = __int_as_float(__builtin_amdgcn_readlane(__float_as_int(h), k + 1));
            float h2v = __int_as_float(__builtin_amdgcn_readlane(__float_as_int(h), k + 2));
            float h3v = __int_as_float(__builtin_amdgcn_readlane(__float_as_int(h), k + 3));
            l0 = fmaf(h0, wf[k], l0);
            l1 = fmaf(h1v, wf[k + 1], l1);
            l2 = fmaf(h2v, wf[k + 2], l2);
            l3 = fmaf(h3v, wf[k + 3], l3);
        }
        float lg = (l0 + l1) + (l2 + l3);
        float m = lg;
        for (int off = 8; off; off >>= 1) m = fmaxf(m, __shfl_xor(m, off, 16));
        float e2 = __expf(lg - m);
        float ssum = e2;
        for (int off = 8; off; off >>= 1) ssum += __shfl_xor(ssum, off, 16);
        if (lane < NP) out[(unsigned)(n * NP) + lane] = e2 / ssum;
        n = n2; vx = vx2; va = va2;
    }
}

extern "C" void kernel_launch(void* const* d_in, const int* in_sizes, int n_in,
                              void* d_out, int out_size, void* d_ws, size_t ws_size,
                              hipStream_t stream) {
    const float* features = (const float*)d_in[0];
    const int*   src      = (const int*)d_in[1];
    const int*   dst      = (const int*)d_in[2];
    const float* Ws1      = (const float*)d_in[3];
    const float* Wn1      = (const float*)d_in[4];
    const float* b1       = (const float*)d_in[5];
    const float* Ws2      = (const float*)d_in[6];
    const float* Wn2      = (const float*)d_in[7];
    const float* b2       = (const float*)d_in[8];
    const float* Wfc      = (const float*)d_in[9];
    const float* bfc      = (const float*)d_in[10];
    float* out = (float*)d_out;

    int nE = in_sizes[1];
    int nN = in_sizes[0] / F;
    int nb = (nN + SCAN_B - 1) / SCAN_B;

    // workspace: deg | rowstart | cursor | bsum(pad) | csr | invd | h1 | agg
    int*   deg      = (int*)d_ws;
    int*   rowstart = deg + nN;
    int*   cursor   = rowstart + nN;
    int*   bsum     = cursor + nN;
    int*   csr      = bsum + ((nb + 255) & ~255);
    float* invd     = (float*)(csr + nE);
    float* h1       = invd + nN;
    float* agg      = h1 + (size_t)nN * F;

    hipMemsetAsync(deg, 0, (size_t)nN * sizeof(int), stream);

    // build CSR
    k_count<<<(nE + 255) / 256, 256, 0, stream>>>(dst, deg, nE);
    k_bsum<<<nb, 256, 0, stream>>>(deg, bsum, nN);
    k_scanb<<<1, 64, 0, stream>>>(bsum, nb);
    k_scanfinal<<<nb, SCAN_B, 0, stream>>>(deg, bsum, rowstart, cursor, invd, nN);
    k_fill<<<(nE + 255) / 256, 256, 0, stream>>>(src, dst, cursor, csr, nE);

    // layer 1
    k_gather<<<4096, 256, 0, stream>>>(features, csr, rowstart, deg, invd, agg, nN);
    k_xform1<<<1024, 256, 0, stream>>>(features, agg, Ws1, Wn1, b1, h1, nN);

    // layer 2 (+FC+softmax)
    k_gather<<<4096, 256, 0, stream>>>(h1, csr, rowstart, deg, invd, agg, nN);
    k_xform2<<<1024, 256, 0, stream>>>(h1, agg, Ws2, Wn2, b2, Wfc, bfc, out, nN);
}